// Round 22
// baseline (73.955 us; speedup 1.0000x reference)
//
#include <hip/hip_runtime.h>
#include <hip/hip_bf16.h>

typedef unsigned short u16;
typedef __attribute__((ext_vector_type(8))) short bf16x8;
typedef __attribute__((ext_vector_type(4))) float f32x4;

#define NE 8
#define NTOPK 4
#define NIN 768
#define NOUT 768
#define NB 16
#define NS 512
#define YSZ (NB * NS * NOUT)   // 6291456
#define EWN (NOUT * NIN)       // 589824

// ---- workspace layout (bytes) ----
#define OFF_PART  0u           // 16*64*768 f32 = 3145728
#define OFF_GATES 3145728u     // 16*8 f32
#define OFF_XBF   3146240u     // 16*512*768 bf16 = 12582912
#define OFF_WD    15729152u    // 8*768*768 bf16  = 9437184
#define OFF_T1T   25166336u    // 8*768*768 bf16
#define OFF_RTW   34603520u    // 8*768*768 bf16
#define OFF_EW    44040704u    // 16*768*768 bf16 = 18874368

// pipeline barriers: counted vmcnt, raw s_barrier (never vmcnt(0) mid-loop)
#define PRE_BAR(N) asm volatile("s_waitcnt vmcnt(" #N ")\n\ts_barrier" ::: "memory")
#define POST_BAR() asm volatile("s_waitcnt lgkmcnt(0)\n\ts_barrier" ::: "memory")

__device__ __forceinline__ u16 f2bf(float f) {
  union { float f; unsigned u; } v; v.f = f;
  unsigned r = v.u + 0x7fffu + ((v.u >> 16) & 1u);
  return (u16)(r >> 16);
}
__device__ __forceinline__ float bf2f(u16 h) {
  union { unsigned u; float f; } v; v.u = ((unsigned)h) << 16;
  return v.f;
}
__device__ __forceinline__ unsigned cvt2(float a, float b) {
  unsigned r;
  asm("v_cvt_pk_bf16_f32 %0, %1, %2" : "=v"(r) : "v"(a), "v"(b));
  return r;
}
__device__ __forceinline__ void gload16(const void* g, void* l) {
  __builtin_amdgcn_global_load_lds(
      (const __attribute__((address_space(1))) unsigned int*)g,
      (__attribute__((address_space(3))) unsigned int*)l, 16, 0, 0);
}
__device__ __forceinline__ void storeC(float* p, float v) { *p = v; }
__device__ __forceinline__ void storeC(u16* p, float v) { *p = f2bf(v); }

// ---------------- k_wd: Wd = bf16(weight - res), 2304 blocks ----------------
__global__ __launch_bounds__(256) void k_wd(const float* __restrict__ w,
                                            const float* __restrict__ res,
                                            u16* __restrict__ Wd) {
  int b2 = blockIdx.x;               // 0..2303
  int e = b2 / 288;
  int blk = b2 % 288;
  size_t base = (size_t)blk * 2048 + threadIdx.x * 8;
  float4 wa = *(const float4*)(w + (size_t)e * EWN + base);
  float4 wb = *(const float4*)(w + (size_t)e * EWN + base + 4);
  float4 ra = *(const float4*)(res + base);
  float4 rb = *(const float4*)(res + base + 4);
  bf16x8 o;
  o[0] = (short)f2bf(wa.x - ra.x); o[1] = (short)f2bf(wa.y - ra.y);
  o[2] = (short)f2bf(wa.z - ra.z); o[3] = (short)f2bf(wa.w - ra.w);
  o[4] = (short)f2bf(wb.x - rb.x); o[5] = (short)f2bf(wb.y - rb.y);
  o[6] = (short)f2bf(wb.z - rb.z); o[7] = (short)f2bf(wb.w - rb.w);
  *(bf16x8*)(Wd + (size_t)e * EWN + base) = o;
}

// ---------------- k_x body: mean partials + x->bf16 (1024 virtual blocks) ----------------
__device__ __forceinline__ void body_x(int u, const float* __restrict__ x,
                                       float* __restrict__ part,
                                       u16* __restrict__ xbf) {
  int t = threadIdx.x;
  if (t < 192) {
    int b = u >> 6;
    int sc = u & 63;
    int c = t * 4;
    float a0 = 0.f, a1 = 0.f, a2 = 0.f, a3 = 0.f;
    int s0 = sc * 8;
#pragma unroll
    for (int r = 0; r < 8; ++r) {
      size_t ro = ((size_t)(b * NS + s0 + r)) * NIN;
      float4 v = *(const float4*)(x + ro + c);
      a0 += v.x; a1 += v.y; a2 += v.z; a3 += v.w;
      ushort4 o;
      o.x = f2bf(v.x); o.y = f2bf(v.y); o.z = f2bf(v.z); o.w = f2bf(v.w);
      *(ushort4*)(xbf + ro + c) = o;
    }
    float4 pv; pv.x = a0; pv.y = a1; pv.z = a2; pv.w = a3;
    *(float4*)(part + (size_t)(b * 64 + sc) * NIN + c) = pv;
  }
}

// ---------------- logits + top-k softmax gates ----------------
__device__ __forceinline__ void body_logits(int b, float* red,
                                            const float* __restrict__ part,
                                            const float* __restrict__ w_gate,
                                            float* __restrict__ gates_out) {
  int tid = threadIdx.x;
  float p[NE] = {0.f, 0.f, 0.f, 0.f, 0.f, 0.f, 0.f, 0.f};
  for (int i = tid; i < NIN; i += 256) {
    float s = 0.f;
#pragma unroll
    for (int sc = 0; sc < 64; ++sc) s += part[(size_t)(b * 64 + sc) * NIN + i];
    float xmv = s * (1.0f / (float)NS);
#pragma unroll
    for (int e = 0; e < NE; ++e) p[e] += xmv * w_gate[i * NE + e];
  }
#pragma unroll
  for (int e = 0; e < NE; ++e) {
    float v = p[e];
    for (int off = 32; off; off >>= 1) v += __shfl_down(v, off);
    if ((tid & 63) == 0) red[(tid >> 6) * NE + e] = v;
  }
  __syncthreads();
  if (tid == 0) {
    float v[NE]; bool used[NE];
    for (int e = 0; e < NE; ++e) {
      v[e] = red[e] + red[NE + e] + red[2 * NE + e] + red[3 * NE + e];
      used[e] = false;
    }
    int idxs[NTOPK]; float vals[NTOPK];
    for (int t = 0; t < NTOPK; ++t) {
      int best = 0; float bv = -3.4e38f;
      for (int e = 0; e < NE; ++e)
        if (!used[e] && v[e] > bv) { bv = v[e]; best = e; }
      used[best] = true; idxs[t] = best; vals[t] = bv;
    }
    float m = vals[0];
    float ex[NTOPK]; float se = 0.f;
    for (int t = 0; t < NTOPK; ++t) { ex[t] = expf(vals[t] - m); se += ex[t]; }
    float g[NE];
    for (int e = 0; e < NE; ++e) g[e] = 0.f;
    for (int t = 0; t < NTOPK; ++t) g[idxs[t]] = ex[t] / se;
    for (int e = 0; e < NE; ++e) gates_out[b * NE + e] = g[e];
  }
}

// ---------------- kron GEMM (proven 64x128): C[e][m][n] = sum_k (c1⊗c2)[m][k]*B[e][n][k] ----------------
__device__ __forceinline__ void body_kron(int bid, u16* lb,
                                          const float* __restrict__ c1,
                                          const float* __restrict__ c2,
                                          const u16* __restrict__ B,
                                          u16* __restrict__ C) {
  const int tid = threadIdx.x;
  const int lane = tid & 63;
  const int w = tid >> 6;
  const int wr = w >> 1, wc = w & 1;
  const int fr = lane & 15;
  const int kq = lane >> 4;
  const int swz = (bid & 7) * 72 + (bid >> 3);
  const int mb = swz % 12;
  const int nb = (swz / 12) % 6;
  const int e = swz / 72;
  const int m0 = mb * 64, n0 = nb * 128;
  const u16* Bb = B + (size_t)e * EWN;
  const float* c1b = c1 + e * 24 * 24;
  const float* c2b = c2 + e * 32 * 32;
  const int r1a = (m0 >> 5) + wr;
  float c2r[2][8];
  {
    const float* p0 = c2b + fr * 32 + kq * 8;
    const float* p1 = c2b + (16 + fr) * 32 + kq * 8;
#pragma unroll
    for (int j = 0; j < 8; ++j) { c2r[0][j] = p0[j]; c2r[1][j] = p1[j]; }
  }
  const int ob1 = (w * 2) * 1024 + lane * 16;
  const int ob2 = ob1 + 1024;
  const int rowB1 = ob1 >> 6, colB1 = ob1 & 63;
  const int rowB2 = ob2 >> 6, colB2 = ob2 & 63;

  auto STAGE = [&](int t) {
    int s = t & 3;
    int k0 = t * 32;
    gload16((const char*)Bb + ((size_t)(n0 + rowB1) * NIN + k0) * 2 + colB1,
            (char*)(lb + s * 4096) + ob1);
    gload16((const char*)Bb + ((size_t)(n0 + rowB2) * NIN + k0) * 2 + colB2,
            (char*)(lb + s * 4096) + ob2);
  };
  f32x4 acc[2][4] = {};
  auto COMPUTE = [&](int t) {
    int s = t & 3;
    const float ca = c1b[r1a * 24 + t];
    bf16x8 aF[2], bF[4];
#pragma unroll
    for (int m = 0; m < 2; ++m) {
      const float* cr = c2r[m];
      union { unsigned u[4]; bf16x8 v; } pk;
      pk.u[0] = cvt2(ca * cr[0], ca * cr[1]);
      pk.u[1] = cvt2(ca * cr[2], ca * cr[3]);
      pk.u[2] = cvt2(ca * cr[4], ca * cr[5]);
      pk.u[3] = cvt2(ca * cr[6], ca * cr[7]);
      aF[m] = pk.v;
    }
#pragma unroll
    for (int n = 0; n < 4; ++n)
      bF[n] = *(const bf16x8*)(lb + (size_t)s * 4096 + (wc * 64 + n * 16 + fr) * 32 + kq * 8);
#pragma unroll
    for (int m = 0; m < 2; ++m)
#pragma unroll
      for (int n = 0; n < 4; ++n)
        acc[m][n] = __builtin_amdgcn_mfma_f32_16x16x32_bf16(aF[m], bF[n], acc[m][n], 0, 0, 0);
  };

  STAGE(0); STAGE(1); STAGE(2); STAGE(3);
  for (int i = 0; i < 10; ++i) {
    PRE_BAR(4);
    COMPUTE(2 * i); COMPUTE(2 * i + 1);
    POST_BAR();
    STAGE(2 * i + 4); STAGE(2 * i + 5);
  }
  PRE_BAR(4);  COMPUTE(20); COMPUTE(21);  POST_BAR();
  PRE_BAR(0);  COMPUTE(22); COMPUTE(23);

  u16* Cb = C + (size_t)e * EWN;
#pragma unroll
  for (int m = 0; m < 2; ++m) {
    int rb = m0 + wr * 32 + m * 16 + kq * 4;
#pragma unroll
    for (int n = 0; n < 4; ++n) {
      int col = n0 + wc * 64 + n * 16 + fr;
#pragma unroll
      for (int r = 0; r < 4; ++r)
        storeC(Cb + (size_t)(rb + r) * NIN + col, acc[m][n][r]);
    }
  }
}

// ---------------- k_A: kronA (blocks 0..575) || k_x (blocks 576..1599) ----------------
__global__ __launch_bounds__(256) void k_A(const float* c1, const float* c2,
                                           const u16* B, u16* C,
                                           const float* __restrict__ x,
                                           float* __restrict__ part,
                                           u16* __restrict__ xbf) {
  __shared__ __attribute__((aligned(128))) u16 lB[4 * 128 * 32];
  if (blockIdx.x < 576) body_kron(blockIdx.x, lB, c1, c2, B, C);
  else                  body_x(blockIdx.x - 576, x, part, xbf);
}

// ---------------- k_B: kronB (blocks 0..575) || logits (576..591) ----------------
__global__ __launch_bounds__(256) void k_B(const float* c1, const float* c2,
                                           const u16* B, u16* C,
                                           const float* part, const float* w_gate,
                                           float* gates) {
  __shared__ __attribute__((aligned(128))) u16 lB[4 * 128 * 32];
  __shared__ float red[NB * NE];
  if (blockIdx.x < 576) body_kron(blockIdx.x, lB, c1, c2, B, C);
  else                  body_logits(blockIdx.x - 576, red, part, w_gate, gates);
}

// ---------------- combine: ew = bf16(res + 0.9*sum_e g*rtw) + loss ----------------
__global__ __launch_bounds__(256) void k_p3(const u16* __restrict__ rtwb,
                                            const float* __restrict__ res,
                                            const float* __restrict__ g,
                                            u16* __restrict__ ew,
                                            float* __restrict__ loss_out) {
  __shared__ float gsh[NB * NE];
  int bid = blockIdx.x;
  int tid = threadIdx.x;
  if (tid < NB * NE) gsh[tid] = 0.9f * g[tid];
  __syncthreads();
  if (bid == 0 && tid == 0) {
    float imp[NE], ld[NE];
    for (int e = 0; e < NE; ++e) {
      float si = 0.f, sl = 0.f;
      for (int b = 0; b < NB; ++b) {
        float gg = g[b * NE + e];
        si += gg; sl += (gg > 0.f) ? 1.f : 0.f;
      }
      imp[e] = si; ld[e] = sl;
    }
    float loss = 0.f;
    for (int which = 0; which < 2; ++which) {
      const float* a = which ? ld : imp;
      float mean = 0.f;
      for (int e = 0; e < NE; ++e) mean += a[e];
      mean *= (1.0f / NE);
      float var = 0.f;
      for (int e = 0; e < NE; ++e) { float d = a[e] - mean; var += d * d; }
      var *= (1.0f / (NE - 1));
      loss += var / (mean * mean + 1e-10f);
    }
    loss_out[0] = 0.01f * loss;
  }
  size_t base = ((size_t)bid * 256 + tid) * 8;
  float rv[NE][8];
#pragma unroll
  for (int e = 0; e < NE; ++e) {
    bf16x8 v = *(const bf16x8*)(rtwb + (size_t)e * EWN + base);
#pragma unroll
    for (int j = 0; j < 8; ++j) rv[e][j] = bf2f((u16)v[j]);
  }
  float r8[8];
  {
    float4 ra = *(const float4*)(res + base);
    float4 rb = *(const float4*)(res + base + 4);
    r8[0] = ra.x; r8[1] = ra.y; r8[2] = ra.z; r8[3] = ra.w;
    r8[4] = rb.x; r8[5] = rb.y; r8[6] = rb.z; r8[7] = rb.w;
  }
  for (int b = 0; b < NB; ++b) {
    float a[8];
#pragma unroll
    for (int j = 0; j < 8; ++j) a[j] = r8[j];
#pragma unroll
    for (int e = 0; e < NE; ++e) {
      float gg = gsh[b * NE + e];
#pragma unroll
      for (int j = 0; j < 8; ++j) a[j] += gg * rv[e][j];
    }
    bf16x8 o;
#pragma unroll
    for (int j = 0; j < 8; ++j) o[j] = (short)f2bf(a[j]);
    *(bf16x8*)(ew + (size_t)b * EWN + base) = o;
  }
}

// ---------------- main GEMM (round-7 proven): BM=64, BN=128, 4-ring paired ----------------
// grid 768 (96/XCD = two batches per XCD) = exactly 3 blocks/CU; 36 KB LDS.
__global__ __launch_bounds__(256) void k_main(const u16* __restrict__ A,
                                              const u16* __restrict__ Bw,
                                              float* __restrict__ C) {
  __shared__ __attribute__((aligned(128))) u16 lA[4][64 * 32];     // 16 KB
  __shared__ __attribute__((aligned(128))) u16 lB[4][128 * 32];    // 32 KB
  const int tid = threadIdx.x;
  const int lane = tid & 63;
  const int w = tid >> 6;
  const int wr = w >> 1, wc = w & 1;
  const int fr = lane & 15;
  const int kq = lane >> 4;
  const int swz = (blockIdx.x & 7) * 96 + (blockIdx.x >> 3);
  const int mb = swz % 8;
  const int nb = (swz / 8) % 6;
  const int b = swz / 48;
  const int m0 = mb * 64, n0 = nb * 128;
  const u16* Ab = A + (size_t)b * NS * NIN;
  const u16* Bb = Bw + (size_t)b * EWN;
  const int obA = tid * 16;
  const int rowA = obA >> 6, colA = obA & 63;
  const int obB1 = (w * 2) * 1024 + lane * 16;
  const int obB2 = obB1 + 1024;
  const int rowB1 = obB1 >> 6, colB1 = obB1 & 63;
  const int rowB2 = obB2 >> 6, colB2 = obB2 & 63;

  auto STAGE = [&](int t) {
    int s = t & 3;
    int k0 = t * 32;
    gload16((const char*)Ab + ((size_t)(m0 + rowA) * NIN + k0) * 2 + colA,
            (char*)&lA[s][0] + obA);
    gload16((const char*)Bb + ((size_t)(n0 + rowB1) * NIN + k0) * 2 + colB1,
            (char*)&lB[s][0] + obB1);
    gload16((const char*)Bb + ((size_t)(n0 + rowB2) * NIN + k0) * 2 + colB2,
            (char*)&lB[s][0] + obB2);
  };
  f32x4 acc[2][4] = {};
  auto COMPUTE = [&](int t) {
    int s = t & 3;
    bf16x8 aF[2], bF[4];
#pragma unroll
    for (int m = 0; m < 2; ++m)
      aF[m] = *(const bf16x8*)&lA[s][(wr * 32 + m * 16 + fr) * 32 + kq * 8];
#pragma unroll
    for (int n = 0; n < 4; ++n)
      bF[n] = *(const bf16x8*)&lB[s][(wc * 64 + n * 16 + fr) * 32 + kq * 8];
#pragma unroll
    for (int m = 0; m < 2; ++m)
#pragma unroll
      for (int n = 0; n < 4; ++n)
        acc[m][n] = __builtin_amdgcn_mfma_f32_16x16x32_bf16(aF[m], bF[n], acc[m][n], 0, 0, 0);
  };

  STAGE(0); STAGE(1); STAGE(2); STAGE(3);       // 4 tiles = 12 loads in flight
  for (int i = 0; i < 10; ++i) {
    PRE_BAR(6);                                 // pair 2i,2i+1 landed (2 tiles = 6 loads fly)
    COMPUTE(2 * i); COMPUTE(2 * i + 1);
    POST_BAR();
    STAGE(2 * i + 4); STAGE(2 * i + 5);
  }
  PRE_BAR(6);  COMPUTE(20); COMPUTE(21);  POST_BAR();
  PRE_BAR(0);  COMPUTE(22); COMPUTE(23);

  float* Cb = C + (size_t)b * NS * NOUT;
#pragma unroll
  for (int m = 0; m < 2; ++m) {
    int rb = m0 + wr * 32 + m * 16 + kq * 4;
#pragma unroll
    for (int n = 0; n < 4; ++n) {
      int col = n0 + wc * 64 + n * 16 + fr;
#pragma unroll
      for (int r = 0; r < 4; ++r)
        Cb[(size_t)(rb + r) * NOUT + col] = acc[m][n][r];
    }
  }
}

extern "C" void kernel_launch(void* const* d_in, const int* in_sizes, int n_in,
                              void* d_out, int out_size, void* d_ws, size_t ws_size,
                              hipStream_t stream) {
  const float* x = (const float*)d_in[0];
  const float* w_gate = (const float*)d_in[1];
  const float* weight = (const float*)d_in[2];
  const float* res_w = (const float*)d_in[3];
  const float* c1i = (const float*)d_in[4];
  const float* c2i = (const float*)d_in[5];
  const float* c1o = (const float*)d_in[6];
  const float* c2o = (const float*)d_in[7];

  char* ws = (char*)d_ws;
  float* part = (float*)(ws + OFF_PART);
  float* gates = (float*)(ws + OFF_GATES);
  u16* xbf = (u16*)(ws + OFF_XBF);
  u16* Wd = (u16*)(ws + OFF_WD);
  u16* T1t = (u16*)(ws + OFF_T1T);
  u16* rtwb = (u16*)(ws + OFF_RTW);
  u16* ew = (u16*)(ws + OFF_EW);

  float* y = (float*)d_out;
  float* loss = y + YSZ;

  // 1) Wd = bf16(weight - res)
  k_wd<<<dim3(2304), 256, 0, stream>>>(weight, res_w, Wd);
  // 2) kron A  ||  k_x (x->xbf, part)
  k_A<<<dim3(1600), 256, 0, stream>>>(c1i, c2i, Wd, T1t, x, part, xbf);
  // 3) kron B  ||  logits
  k_B<<<dim3(592), 256, 0, stream>>>(c1o, c2o, T1t, rtwb, part, w_gate, gates);
  // 4) combine + loss
  k_p3<<<dim3(288), 256, 0, stream>>>(rtwb, res_w, gates, ew, loss);
  // 5) main grouped GEMM (round-7 proven 64x128, grid 768 = 3 blocks/CU)
  k_main<<<dim3(768), 256, 0, stream>>>(xbf, ew, y);
}

// Round 23
// 72.657 us; speedup vs baseline: 1.0179x; 1.0179x over previous
//
#include <hip/hip_runtime.h>
#include <hip/hip_bf16.h>

typedef unsigned short u16;
typedef __attribute__((ext_vector_type(8))) short bf16x8;
typedef __attribute__((ext_vector_type(4))) float f32x4;

#define NE 8
#define NTOPK 4
#define NIN 768
#define NOUT 768
#define NB 16
#define NS 512
#define YSZ (NB * NS * NOUT)   // 6291456
#define EWN (NOUT * NIN)       // 589824

// ---- workspace layout (bytes) ----
#define OFF_PART  0u           // 16*64*768 f32 = 3145728
#define OFF_GATES 3145728u     // 16*8 f32
#define OFF_XBF   3146240u     // 16*512*768 bf16 = 12582912
#define OFF_WD    15729152u    // 8*768*768 bf16  = 9437184
#define OFF_T1T   25166336u    // 8*768*768 bf16
#define OFF_RTW   34603520u    // 8*768*768 bf16
#define OFF_EW    44040704u    // 16*768*768 bf16 = 18874368

// pipeline barriers: counted vmcnt, raw s_barrier (never vmcnt(0) mid-loop)
#define PRE_BAR(N) asm volatile("s_waitcnt vmcnt(" #N ")\n\ts_barrier" ::: "memory")
#define POST_BAR() asm volatile("s_waitcnt lgkmcnt(0)\n\ts_barrier" ::: "memory")

__device__ __forceinline__ u16 f2bf(float f) {
  union { float f; unsigned u; } v; v.f = f;
  unsigned r = v.u + 0x7fffu + ((v.u >> 16) & 1u);
  return (u16)(r >> 16);
}
__device__ __forceinline__ float bf2f(u16 h) {
  union { unsigned u; float f; } v; v.u = ((unsigned)h) << 16;
  return v.f;
}
__device__ __forceinline__ unsigned cvt2(float a, float b) {
  unsigned r;
  asm("v_cvt_pk_bf16_f32 %0, %1, %2" : "=v"(r) : "v"(a), "v"(b));
  return r;
}
__device__ __forceinline__ void gload16(const void* g, void* l) {
  __builtin_amdgcn_global_load_lds(
      (const __attribute__((address_space(1))) unsigned int*)g,
      (__attribute__((address_space(3))) unsigned int*)l, 16, 0, 0);
}
__device__ __forceinline__ void storeC(float* p, float v) { *p = v; }
__device__ __forceinline__ void storeC(u16* p, float v) { *p = f2bf(v); }

// ---------------- k_wd: Wd = bf16(weight - res), 2304 blocks ----------------
__global__ __launch_bounds__(256) void k_wd(const float* __restrict__ w,
                                            const float* __restrict__ res,
                                            u16* __restrict__ Wd) {
  int b2 = blockIdx.x;               // 0..2303
  int e = b2 / 288;
  int blk = b2 % 288;
  size_t base = (size_t)blk * 2048 + threadIdx.x * 8;
  float4 wa = *(const float4*)(w + (size_t)e * EWN + base);
  float4 wb = *(const float4*)(w + (size_t)e * EWN + base + 4);
  float4 ra = *(const float4*)(res + base);
  float4 rb = *(const float4*)(res + base + 4);
  bf16x8 o;
  o[0] = (short)f2bf(wa.x - ra.x); o[1] = (short)f2bf(wa.y - ra.y);
  o[2] = (short)f2bf(wa.z - ra.z); o[3] = (short)f2bf(wa.w - ra.w);
  o[4] = (short)f2bf(wb.x - rb.x); o[5] = (short)f2bf(wb.y - rb.y);
  o[6] = (short)f2bf(wb.z - rb.z); o[7] = (short)f2bf(wb.w - rb.w);
  *(bf16x8*)(Wd + (size_t)e * EWN + base) = o;
}

// ---------------- k_x body: mean partials + x->bf16 (1024 virtual blocks) ----------------
__device__ __forceinline__ void body_x(int u, const float* __restrict__ x,
                                       float* __restrict__ part,
                                       u16* __restrict__ xbf) {
  int t = threadIdx.x;
  if (t < 192) {
    int b = u >> 6;
    int sc = u & 63;
    int c = t * 4;
    float a0 = 0.f, a1 = 0.f, a2 = 0.f, a3 = 0.f;
    int s0 = sc * 8;
#pragma unroll
    for (int r = 0; r < 8; ++r) {
      size_t ro = ((size_t)(b * NS + s0 + r)) * NIN;
      float4 v = *(const float4*)(x + ro + c);
      a0 += v.x; a1 += v.y; a2 += v.z; a3 += v.w;
      ushort4 o;
      o.x = f2bf(v.x); o.y = f2bf(v.y); o.z = f2bf(v.z); o.w = f2bf(v.w);
      *(ushort4*)(xbf + ro + c) = o;
    }
    float4 pv; pv.x = a0; pv.y = a1; pv.z = a2; pv.w = a3;
    *(float4*)(part + (size_t)(b * 64 + sc) * NIN + c) = pv;
  }
}

// ---------------- logits + top-k softmax gates ----------------
__device__ __forceinline__ void body_logits(int b, float* red,
                                            const float* __restrict__ part,
                                            const float* __restrict__ w_gate,
                                            float* __restrict__ gates_out) {
  int tid = threadIdx.x;
  float p[NE] = {0.f, 0.f, 0.f, 0.f, 0.f, 0.f, 0.f, 0.f};
  for (int i = tid; i < NIN; i += 256) {
    float s = 0.f;
#pragma unroll
    for (int sc = 0; sc < 64; ++sc) s += part[(size_t)(b * 64 + sc) * NIN + i];
    float xmv = s * (1.0f / (float)NS);
#pragma unroll
    for (int e = 0; e < NE; ++e) p[e] += xmv * w_gate[i * NE + e];
  }
#pragma unroll
  for (int e = 0; e < NE; ++e) {
    float v = p[e];
    for (int off = 32; off; off >>= 1) v += __shfl_down(v, off);
    if ((tid & 63) == 0) red[(tid >> 6) * NE + e] = v;
  }
  __syncthreads();
  if (tid == 0) {
    float v[NE]; bool used[NE];
    for (int e = 0; e < NE; ++e) {
      v[e] = red[e] + red[NE + e] + red[2 * NE + e] + red[3 * NE + e];
      used[e] = false;
    }
    int idxs[NTOPK]; float vals[NTOPK];
    for (int t = 0; t < NTOPK; ++t) {
      int best = 0; float bv = -3.4e38f;
      for (int e = 0; e < NE; ++e)
        if (!used[e] && v[e] > bv) { bv = v[e]; best = e; }
      used[best] = true; idxs[t] = best; vals[t] = bv;
    }
    float m = vals[0];
    float ex[NTOPK]; float se = 0.f;
    for (int t = 0; t < NTOPK; ++t) { ex[t] = expf(vals[t] - m); se += ex[t]; }
    float g[NE];
    for (int e = 0; e < NE; ++e) g[e] = 0.f;
    for (int t = 0; t < NTOPK; ++t) g[idxs[t]] = ex[t] / se;
    for (int e = 0; e < NE; ++e) gates_out[b * NE + e] = g[e];
  }
}

// ---------------- kron GEMM (proven 64x128): C[e][m][n] = sum_k (c1⊗c2)[m][k]*B[e][n][k] ----------------
__device__ __forceinline__ void body_kron(int bid, u16* lb,
                                          const float* __restrict__ c1,
                                          const float* __restrict__ c2,
                                          const u16* __restrict__ B,
                                          u16* __restrict__ C) {
  const int tid = threadIdx.x;
  const int lane = tid & 63;
  const int w = tid >> 6;
  const int wr = w >> 1, wc = w & 1;
  const int fr = lane & 15;
  const int kq = lane >> 4;
  const int swz = (bid & 7) * 72 + (bid >> 3);
  const int mb = swz % 12;
  const int nb = (swz / 12) % 6;
  const int e = swz / 72;
  const int m0 = mb * 64, n0 = nb * 128;
  const u16* Bb = B + (size_t)e * EWN;
  const float* c1b = c1 + e * 24 * 24;
  const float* c2b = c2 + e * 32 * 32;
  const int r1a = (m0 >> 5) + wr;
  float c2r[2][8];
  {
    const float* p0 = c2b + fr * 32 + kq * 8;
    const float* p1 = c2b + (16 + fr) * 32 + kq * 8;
#pragma unroll
    for (int j = 0; j < 8; ++j) { c2r[0][j] = p0[j]; c2r[1][j] = p1[j]; }
  }
  const int ob1 = (w * 2) * 1024 + lane * 16;
  const int ob2 = ob1 + 1024;
  const int rowB1 = ob1 >> 6, colB1 = ob1 & 63;
  const int rowB2 = ob2 >> 6, colB2 = ob2 & 63;

  auto STAGE = [&](int t) {
    int s = t & 3;
    int k0 = t * 32;
    gload16((const char*)Bb + ((size_t)(n0 + rowB1) * NIN + k0) * 2 + colB1,
            (char*)(lb + s * 4096) + ob1);
    gload16((const char*)Bb + ((size_t)(n0 + rowB2) * NIN + k0) * 2 + colB2,
            (char*)(lb + s * 4096) + ob2);
  };
  f32x4 acc[2][4] = {};
  auto COMPUTE = [&](int t) {
    int s = t & 3;
    const float ca = c1b[r1a * 24 + t];
    bf16x8 aF[2], bF[4];
#pragma unroll
    for (int m = 0; m < 2; ++m) {
      const float* cr = c2r[m];
      union { unsigned u[4]; bf16x8 v; } pk;
      pk.u[0] = cvt2(ca * cr[0], ca * cr[1]);
      pk.u[1] = cvt2(ca * cr[2], ca * cr[3]);
      pk.u[2] = cvt2(ca * cr[4], ca * cr[5]);
      pk.u[3] = cvt2(ca * cr[6], ca * cr[7]);
      aF[m] = pk.v;
    }
#pragma unroll
    for (int n = 0; n < 4; ++n)
      bF[n] = *(const bf16x8*)(lb + (size_t)s * 4096 + (wc * 64 + n * 16 + fr) * 32 + kq * 8);
#pragma unroll
    for (int m = 0; m < 2; ++m)
#pragma unroll
      for (int n = 0; n < 4; ++n)
        acc[m][n] = __builtin_amdgcn_mfma_f32_16x16x32_bf16(aF[m], bF[n], acc[m][n], 0, 0, 0);
  };

  STAGE(0); STAGE(1); STAGE(2); STAGE(3);
  for (int i = 0; i < 10; ++i) {
    PRE_BAR(4);
    COMPUTE(2 * i); COMPUTE(2 * i + 1);
    POST_BAR();
    STAGE(2 * i + 4); STAGE(2 * i + 5);
  }
  PRE_BAR(4);  COMPUTE(20); COMPUTE(21);  POST_BAR();
  PRE_BAR(0);  COMPUTE(22); COMPUTE(23);

  u16* Cb = C + (size_t)e * EWN;
#pragma unroll
  for (int m = 0; m < 2; ++m) {
    int rb = m0 + wr * 32 + m * 16 + kq * 4;
#pragma unroll
    for (int n = 0; n < 4; ++n) {
      int col = n0 + wc * 64 + n * 16 + fr;
#pragma unroll
      for (int r = 0; r < 4; ++r)
        storeC(Cb + (size_t)(rb + r) * NIN + col, acc[m][n][r]);
    }
  }
}

// ---------------- k_A: kronA (blocks 0..575) || k_x (blocks 576..1599) ----------------
__global__ __launch_bounds__(256) void k_A(const float* c1, const float* c2,
                                           const u16* B, u16* C,
                                           const float* __restrict__ x,
                                           float* __restrict__ part,
                                           u16* __restrict__ xbf) {
  __shared__ __attribute__((aligned(128))) u16 lB[4 * 128 * 32];
  if (blockIdx.x < 576) body_kron(blockIdx.x, lB, c1, c2, B, C);
  else                  body_x(blockIdx.x - 576, x, part, xbf);
}

// ---------------- k_B: kronB (blocks 0..575) || logits (576..591) ----------------
__global__ __launch_bounds__(256) void k_B(const float* c1, const float* c2,
                                           const u16* B, u16* C,
                                           const float* part, const float* w_gate,
                                           float* gates) {
  __shared__ __attribute__((aligned(128))) u16 lB[4 * 128 * 32];
  __shared__ float red[NB * NE];
  if (blockIdx.x < 576) body_kron(blockIdx.x, lB, c1, c2, B, C);
  else                  body_logits(blockIdx.x - 576, red, part, w_gate, gates);
}

// ---------------- combine: ew = bf16(res + 0.9*sum_e g*rtw) + loss ----------------
__global__ __launch_bounds__(256) void k_p3(const u16* __restrict__ rtwb,
                                            const float* __restrict__ res,
                                            const float* __restrict__ g,
                                            u16* __restrict__ ew,
                                            float* __restrict__ loss_out) {
  __shared__ float gsh[NB * NE];
  int bid = blockIdx.x;
  int tid = threadIdx.x;
  if (tid < NB * NE) gsh[tid] = 0.9f * g[tid];
  __syncthreads();
  if (bid == 0 && tid == 0) {
    float imp[NE], ld[NE];
    for (int e = 0; e < NE; ++e) {
      float si = 0.f, sl = 0.f;
      for (int b = 0; b < NB; ++b) {
        float gg = g[b * NE + e];
        si += gg; sl += (gg > 0.f) ? 1.f : 0.f;
      }
      imp[e] = si; ld[e] = sl;
    }
    float loss = 0.f;
    for (int which = 0; which < 2; ++which) {
      const float* a = which ? ld : imp;
      float mean = 0.f;
      for (int e = 0; e < NE; ++e) mean += a[e];
      mean *= (1.0f / NE);
      float var = 0.f;
      for (int e = 0; e < NE; ++e) { float d = a[e] - mean; var += d * d; }
      var *= (1.0f / (NE - 1));
      loss += var / (mean * mean + 1e-10f);
    }
    loss_out[0] = 0.01f * loss;
  }
  size_t base = ((size_t)bid * 256 + tid) * 8;
  float rv[NE][8];
#pragma unroll
  for (int e = 0; e < NE; ++e) {
    bf16x8 v = *(const bf16x8*)(rtwb + (size_t)e * EWN + base);
#pragma unroll
    for (int j = 0; j < 8; ++j) rv[e][j] = bf2f((u16)v[j]);
  }
  float r8[8];
  {
    float4 ra = *(const float4*)(res + base);
    float4 rb = *(const float4*)(res + base + 4);
    r8[0] = ra.x; r8[1] = ra.y; r8[2] = ra.z; r8[3] = ra.w;
    r8[4] = rb.x; r8[5] = rb.y; r8[6] = rb.z; r8[7] = rb.w;
  }
  for (int b = 0; b < NB; ++b) {
    float a[8];
#pragma unroll
    for (int j = 0; j < 8; ++j) a[j] = r8[j];
#pragma unroll
    for (int e = 0; e < NE; ++e) {
      float gg = gsh[b * NE + e];
#pragma unroll
      for (int j = 0; j < 8; ++j) a[j] += gg * rv[e][j];
    }
    bf16x8 o;
#pragma unroll
    for (int j = 0; j < 8; ++j) o[j] = (short)f2bf(a[j]);
    *(bf16x8*)(ew + (size_t)b * EWN + base) = o;
  }
}

// ---------------- main GEMM: 128x128 tile, 3-buffer ring, paired regions ----------------
// grid 384 (48/XCD = two batches per XCD), 48KB LDS, 12 barrier regions.
__global__ __launch_bounds__(256) void k_main(const u16* __restrict__ A,
                                              const u16* __restrict__ Bw,
                                              float* __restrict__ C) {
  __shared__ __attribute__((aligned(128))) u16 la[3 * 128 * 32];   // 24 KB
  __shared__ __attribute__((aligned(128))) u16 lb[3 * 128 * 32];   // 24 KB
  const int tid = threadIdx.x;
  const int lane = tid & 63;
  const int w = tid >> 6;
  const int wr = w >> 1, wc = w & 1;
  const int fr = lane & 15;
  const int kq = lane >> 4;
  const int swz = (blockIdx.x & 7) * 48 + (blockIdx.x >> 3);
  const int mb = swz % 4;
  const int nb = (swz / 4) % 6;
  const int b = swz / 24;
  const int m0 = mb * 128, n0 = nb * 128;
  const u16* Ab = A + (size_t)b * NS * NIN;
  const u16* Bb = Bw + (size_t)b * EWN;
  const int ob1 = tid * 16;            // first 4KB half (rows 0..63)
  const int ob2 = ob1 + 4096;          // second 4KB half (rows 64..127)
  const int row1 = ob1 >> 6, col1 = ob1 & 63;
  const int row2 = ob2 >> 6, col2 = ob2 & 63;

  auto STAGE = [&](int t) {
    int s = t % 3;
    int k0 = t * 32;
    gload16((const char*)Ab + ((size_t)(m0 + row1) * NIN + k0) * 2 + col1,
            (char*)(la + s * 4096) + ob1);
    gload16((const char*)Ab + ((size_t)(m0 + row2) * NIN + k0) * 2 + col2,
            (char*)(la + s * 4096) + ob2);
    gload16((const char*)Bb + ((size_t)(n0 + row1) * NIN + k0) * 2 + col1,
            (char*)(lb + s * 4096) + ob1);
    gload16((const char*)Bb + ((size_t)(n0 + row2) * NIN + k0) * 2 + col2,
            (char*)(lb + s * 4096) + ob2);
  };
  f32x4 acc[4][4] = {};
  auto COMPUTE = [&](int t) {
    int s = t % 3;
    bf16x8 aF[4], bF[4];
#pragma unroll
    for (int m = 0; m < 4; ++m)
      aF[m] = *(const bf16x8*)(la + (size_t)s * 4096 + (wr * 64 + m * 16 + fr) * 32 + kq * 8);
#pragma unroll
    for (int n = 0; n < 4; ++n)
      bF[n] = *(const bf16x8*)(lb + (size_t)s * 4096 + (wc * 64 + n * 16 + fr) * 32 + kq * 8);
#pragma unroll
    for (int m = 0; m < 4; ++m)
#pragma unroll
      for (int n = 0; n < 4; ++n)
        acc[m][n] = __builtin_amdgcn_mfma_f32_16x16x32_bf16(aF[m], bF[n], acc[m][n], 0, 0, 0);
  };

  STAGE(0); STAGE(1); STAGE(2);
  for (int i = 0; i < 10; ++i) {
    PRE_BAR(4);
    COMPUTE(2 * i); COMPUTE(2 * i + 1);
    POST_BAR();
    STAGE(2 * i + 3); STAGE(2 * i + 4);
  }
  PRE_BAR(4);  COMPUTE(20); COMPUTE(21);  POST_BAR();
  STAGE(23);
  PRE_BAR(0);  COMPUTE(22); COMPUTE(23);

  float* Cb = C + (size_t)b * NS * NOUT;
#pragma unroll
  for (int m = 0; m < 4; ++m) {
    int rb = m0 + wr * 64 + m * 16 + kq * 4;
#pragma unroll
    for (int n = 0; n < 4; ++n) {
      int col = n0 + wc * 64 + n * 16 + fr;
#pragma unroll
      for (int r = 0; r < 4; ++r)
        Cb[(size_t)(rb + r) * NOUT + col] = acc[m][n][r];
    }
  }
}

extern "C" void kernel_launch(void* const* d_in, const int* in_sizes, int n_in,
                              void* d_out, int out_size, void* d_ws, size_t ws_size,
                              hipStream_t stream) {
  const float* x = (const float*)d_in[0];
  const float* w_gate = (const float*)d_in[1];
  const float* weight = (const float*)d_in[2];
  const float* res_w = (const float*)d_in[3];
  const float* c1i = (const float*)d_in[4];
  const float* c2i = (const float*)d_in[5];
  const float* c1o = (const float*)d_in[6];
  const float* c2o = (const float*)d_in[7];

  char* ws = (char*)d_ws;
  float* part = (float*)(ws + OFF_PART);
  float* gates = (float*)(ws + OFF_GATES);
  u16* xbf = (u16*)(ws + OFF_XBF);
  u16* Wd = (u16*)(ws + OFF_WD);
  u16* T1t = (u16*)(ws + OFF_T1T);
  u16* rtwb = (u16*)(ws + OFF_RTW);
  u16* ew = (u16*)(ws + OFF_EW);

  float* y = (float*)d_out;
  float* loss = y + YSZ;

  // 1) Wd = bf16(weight - res)          (~4.5 us, only dep of kron A)
  k_wd<<<dim3(2304), 256, 0, stream>>>(weight, res_w, Wd);
  // 2) kron A  ||  k_x (x->xbf, part)   (x-phase hidden under kron A)
  k_A<<<dim3(1600), 256, 0, stream>>>(c1i, c2i, Wd, T1t, x, part, xbf);
  // 3) kron B  ||  logits               (logits hidden under kron B)
  k_B<<<dim3(592), 256, 0, stream>>>(c1o, c2o, T1t, rtwb, part, w_gate, gates);
  // 4) combine + loss
  k_p3<<<dim3(288), 256, 0, stream>>>(rtwb, res_w, gates, ew, loss);
  // 5) main grouped GEMM (128x128, 3-ring paired — best measured)
  k_main<<<dim3(384), 256, 0, stream>>>(xbf, ew, y);
}